// Round 6
// baseline (71.825 us; speedup 1.0000x reference)
//
#include <hip/hip_runtime.h>
#include <hip/hip_bf16.h>

typedef unsigned short u16;
typedef __bf16 bf16x8 __attribute__((ext_vector_type(8)));
typedef float f32x4 __attribute__((ext_vector_type(4)));
typedef unsigned short ushort8 __attribute__((ext_vector_type(8)));

#define C_IN   128
#define C_OUT  256
#define BATCH  16
#define LEN    4096
#define KS     9
#define PAD    4
#define LPAD   (LEN + 2*PAD)      // 4104
#define KTOT   (C_IN * KS)        // 1152
#define NSTEP  36                 // K = 1152 / 32

#define XT_BLKS    1040           // 65 * 16
#define W4_BLKS    1152
#define EB_BLKS    256

__device__ inline u16 f2bf(float f) {
    __hip_bfloat16 h = __float2bfloat16(f);
    return __builtin_bit_cast(u16, h);
}

// async global->LDS, 16B per lane, wave-uniform LDS base + lane*16
__device__ __forceinline__ void g2l16(const void* g, void* l) {
    __builtin_amdgcn_global_load_lds(
        (const __attribute__((address_space(1))) void*)g,
        (__attribute__((address_space(3))) void*)l, 16, 0, 0);
}

// ---------------------------------------------------------------------------
// Fused prep (one launch):
//  blocks [0,1040): x [B][C][L] f32 -> xt [B][LPAD][C] bf16, edge-padded,
//    4-bit XOR swizzle (16B-block idx ^= l&15) baked into global layout.
//  blocks [1040,2192): weight -> w4 lane-order fragment layout
//    elem = ((s*16 + ob16)*64 + kgrp*16 + mrow)*8 + e,
//    o = ob16*16+mrow, k = s>>2, c = (s&3)*32+kgrp*8+e.
//  blocks [2192,2448): ebias[o] = bias[o] + sum offset*W; block 2192: phys.
// ---------------------------------------------------------------------------
__global__ void prep_all(const float* __restrict__ x, const float* __restrict__ w,
                         const float* __restrict__ bias, const float* __restrict__ vel,
                         const float* __restrict__ acc_in,
                         u16* __restrict__ xt, u16* __restrict__ w4,
                         float* __restrict__ ebias, float* __restrict__ phys_out) {
    int bid = blockIdx.x;
    int t = threadIdx.x;
    if (bid < XT_BLKS) {
        int b    = bid / 65;
        int lblk = bid % 65;
        int lane = t & 63;
        int jb   = t >> 6;
        int lp   = lblk * 64 + lane;
        if (lp >= LPAD) return;
        int l = lp - PAD;
        l = l < 0 ? 0 : (l > LEN - 1 ? LEN - 1 : l);
        const float* xb = x + (size_t)b * C_IN * LEN + l;
        u16* row = xt + ((size_t)b * LPAD + lp) * C_IN;
        int key = lp & 15;
        #pragma unroll
        for (int jj = 0; jj < 4; ++jj) {
            int cblk = jb * 4 + jj;
            ushort8 v;
            #pragma unroll
            for (int e = 0; e < 8; ++e)
                v[e] = f2bf(xb[(size_t)(cblk * 8 + e) * LEN]);
            int jstore = cblk ^ key;
            *reinterpret_cast<ushort8*>(row + jstore * 8) = v;
        }
        return;
    }
    if (bid < XT_BLKS + W4_BLKS) {
        int i = (bid - XT_BLKS) * 256 + t;   // exact: 1152*256 == C_OUT*KTOT
        int e  = i & 7;
        int r  = i >> 3;
        int mr = r & 15;
        int kg = (r >> 4) & 3;
        int ob = (r >> 6) & 15;
        int s  = r >> 10;
        int o  = ob * 16 + mr;
        int k  = s >> 2;
        int c  = (s & 3) * 32 + kg * 8 + e;
        w4[i] = f2bf(w[((size_t)o * C_IN + c) * KS + k]);
        return;
    }
    __shared__ float red[256];
    int o = bid - (XT_BLKS + W4_BLKS);
    float sum = 0.f;
    for (int i = t; i < KTOT; i += 256) {
        int k = i % KS;                    // offset layout [c][k]
        float tk = k * 0.01f;              // DT
        float off = vel[i] * tk + 0.5f * acc_in[i] * tk * tk;
        sum += off * w[(size_t)o * KTOT + i];
    }
    red[t] = sum;
    __syncthreads();
    for (int h = 128; h > 0; h >>= 1) {
        if (t < h) red[t] += red[t + h];
        __syncthreads();
    }
    if (t == 0) ebias[o] = bias[o] + red[0];

    if (o == 0) {                          // phys
        __syncthreads();
        float pv = 0.f;
        for (int i = t; i < KTOT; i += 256) {
            float v = vel[i], a = acc_in[i];
            pv += v * v + a * a;
        }
        red[t] = pv;
        __syncthreads();
        for (int h = 128; h > 0; h >>= 1) {
            if (t < h) red[t] += red[t + h];
            __syncthreads();
        }
        if (t == 0) *phys_out = 0.01f * (red[0] / (float)KTOT);
    }
}

// ---------------------------------------------------------------------------
// Main: implicit-GEMM conv. Block = 256 o x 128 l, 4 waves, wave tile
// 64 o x 128 l (wm in 0..3), 4x8 frags of mfma_f32_16x16x32_bf16.
//  - B (x-tile, 34816B) staged ONCE via global_load_lds (swizzle in data);
//    the ONLY barrier is after this prologue.
//  - A loaded global->VGPR per wave (each wave owns distinct o-rows: zero
//    duplication; w4 lane-order layout => each frag = contiguous coalesced
//    1KB global_load_dwordx4 from L2-resident w4), register double-buffered
//    at distance 1; compiler's counted vmcnt-before-first-use replaces the
//    R5 per-step vmcnt(0)+barrier drain that was serializing the loop.
// ---------------------------------------------------------------------------
__global__ __launch_bounds__(256, 2) void conv_main(const u16* __restrict__ xt,
                                                    const u16* __restrict__ w4,
                                                    const float* __restrict__ ebias,
                                                    float* __restrict__ out) {
    __shared__ u16 ldsx[17408];            // B tile, 34816 B

    int b     = blockIdx.y;
    int lbase = blockIdx.x * 128;
    int t     = threadIdx.x;
    int lane  = t & 63;
    int w     = t >> 6;
    int wm    = w;                         // wave o-quarter: o in [wm*64, wm*64+64)
    int mrow  = lane & 15;
    int kgrp  = lane >> 4;

    // ---- prologue: stage B (34816B) via global_load_lds
    {
        const u16* bsrc = xt + ((size_t)b * LPAD + lbase) * C_IN;
        #pragma unroll
        for (int j = 0; j < 8; ++j)
            g2l16(bsrc + (j * 256 + t) * 8, ldsx + (j * 256 + w * 64) * 8);
        if (t < 128)
            g2l16(bsrc + (2048 + t) * 8, ldsx + (2048 + w * 64) * 8);
    }
    __syncthreads();                       // the only block-wide barrier

    f32x4 acc[4][8] = {};
    const char* ldsbase = reinterpret_cast<const char*>(ldsx);
    // lane-order A: wave's frag (s, mi) at elems ((s*16 + wm*4 + mi)*64 + lane)*8
    const u16* alane = w4 + ((size_t)(wm * 4) * 64 + lane) * 8;

    #define LOAD_A(S, AF)                                                        \
        {                                                                        \
            const u16* p_ = alane + (size_t)(S) * 8192;                          \
            _Pragma("unroll")                                                    \
            for (int mi = 0; mi < 4; ++mi)                                       \
                AF[mi] = *reinterpret_cast<const bf16x8*>(p_ + mi * 512);        \
        }
    #define STEP(S, AF)                                                          \
        {                                                                        \
            int k_ = (S) >> 2;                                                   \
            int coff_ = ((S) & 3) * 64 + kgrp * 16;                              \
            bf16x8 bf_[8];                                                       \
            _Pragma("unroll")                                                    \
            for (int ni = 0; ni < 8; ++ni) {                                     \
                int row_  = ni * 16 + mrow + k_;                                 \
                int addr_ = row_ * 256 + coff_;                                  \
                addr_ ^= (row_ & 15) << 4;                                       \
                bf_[ni] = *reinterpret_cast<const bf16x8*>(ldsbase + addr_);     \
            }                                                                    \
            _Pragma("unroll")                                                    \
            for (int mi = 0; mi < 4; ++mi)                                       \
                _Pragma("unroll")                                                \
                for (int ni = 0; ni < 8; ++ni)                                   \
                    acc[mi][ni] = __builtin_amdgcn_mfma_f32_16x16x32_bf16(       \
                        AF[mi], bf_[ni], acc[mi][ni], 0, 0, 0);                  \
        }

    bf16x8 afA[4], afB[4];
    LOAD_A(0, afA);

    #pragma unroll
    for (int s = 0; s < NSTEP; s += 2) {
        if (s + 1 < NSTEP) LOAD_A(s + 1, afB);   // prefetch next (global, L2)
        STEP(s, afA);
        if (s + 2 < NSTEP) LOAD_A(s + 2, afA);
        STEP(s + 1, afB);
    }

    // ---- epilogue: D layout col = lane&15 (l), row = (lane>>4)*4 + r (o)
    #pragma unroll
    for (int mi = 0; mi < 4; ++mi) {
        int o0 = wm * 64 + mi * 16 + kgrp * 4;
        f32x4 eb = *reinterpret_cast<const f32x4*>(ebias + o0);
        #pragma unroll
        for (int ni = 0; ni < 8; ++ni) {
            int l = lbase + ni * 16 + mrow;
            float* op = out + (size_t)(b * C_OUT + o0) * LEN + l;
            #pragma unroll
            for (int r = 0; r < 4; ++r)
                op[(size_t)r * LEN] = acc[mi][ni][r] + eb[r];
        }
    }
    #undef LOAD_A
    #undef STEP
}

extern "C" void kernel_launch(void* const* d_in, const int* in_sizes, int n_in,
                              void* d_out, int out_size, void* d_ws, size_t ws_size,
                              hipStream_t stream) {
    const float* x      = (const float*)d_in[0];
    const float* weight = (const float*)d_in[1];
    const float* bias   = (const float*)d_in[2];
    const float* vel    = (const float*)d_in[3];
    const float* acc    = (const float*)d_in[4];
    float* out = (float*)d_out;

    char* ws = (char*)d_ws;
    u16*  xt    = (u16*)ws;                                       // 16,797,696 B
    u16*  w4    = (u16*)(ws + (size_t)BATCH * LPAD * C_IN * 2);   // 589,824 B
    float* ebias = (float*)(ws + (size_t)BATCH * LPAD * C_IN * 2 + (size_t)C_OUT * KTOT * 2);

    hipLaunchKernelGGL(prep_all, dim3(XT_BLKS + W4_BLKS + EB_BLKS), dim3(256), 0, stream,
                       x, weight, bias, vel, acc, xt, w4, ebias,
                       out + (size_t)BATCH * C_OUT * LEN);
    hipLaunchKernelGGL(conv_main, dim3(LEN / 128, BATCH), dim3(256), 0, stream,
                       xt, w4, ebias, out);
}

// Round 7
// 66.616 us; speedup vs baseline: 1.0782x; 1.0782x over previous
//
#include <hip/hip_runtime.h>
#include <hip/hip_bf16.h>

typedef unsigned short u16;
typedef __bf16 bf16x8 __attribute__((ext_vector_type(8)));
typedef float f32x4 __attribute__((ext_vector_type(4)));
typedef unsigned short ushort8 __attribute__((ext_vector_type(8)));

#define C_IN   128
#define C_OUT  256
#define BATCH  16
#define LEN    4096
#define KS     9
#define PAD    4
#define LPAD   (LEN + 2*PAD)      // 4104
#define KTOT   (C_IN * KS)        // 1152
#define NSTEP  36                 // K = 1152 / 32

#define XT_BLKS    1040           // 65 * 16
#define W4_BLKS    1152
#define EB_BLKS    256

__device__ inline u16 f2bf(float f) {
    __hip_bfloat16 h = __float2bfloat16(f);
    return __builtin_bit_cast(u16, h);
}

// async global->LDS, 16B per lane, wave-uniform LDS base + lane*16
__device__ __forceinline__ void g2l16(const void* g, void* l) {
    __builtin_amdgcn_global_load_lds(
        (const __attribute__((address_space(1))) void*)g,
        (__attribute__((address_space(3))) void*)l, 16, 0, 0);
}

// ---------------------------------------------------------------------------
// Fused prep (one launch):
//  blocks [0,1040): x [B][C][L] f32 -> xt [B][LPAD][C] bf16, edge-padded,
//    4-bit XOR swizzle (16B-block idx ^= l&15) baked into global layout.
//  blocks [1040,2192): weight -> w4 lane-order fragment layout
//    elem = ((s*16 + ob16)*64 + kgrp*16 + mrow)*8 + e,
//    o = ob16*16+mrow, k = s>>2, c = (s&3)*32+kgrp*8+e.
//  blocks [2192,2448): ebias[o] = bias[o] + sum offset*W; block 2192: phys.
// ---------------------------------------------------------------------------
__global__ void prep_all(const float* __restrict__ x, const float* __restrict__ w,
                         const float* __restrict__ bias, const float* __restrict__ vel,
                         const float* __restrict__ acc_in,
                         u16* __restrict__ xt, u16* __restrict__ w4,
                         float* __restrict__ ebias, float* __restrict__ phys_out) {
    int bid = blockIdx.x;
    int t = threadIdx.x;
    if (bid < XT_BLKS) {
        int b    = bid / 65;
        int lblk = bid % 65;
        int lane = t & 63;
        int jb   = t >> 6;
        int lp   = lblk * 64 + lane;
        if (lp >= LPAD) return;
        int l = lp - PAD;
        l = l < 0 ? 0 : (l > LEN - 1 ? LEN - 1 : l);
        const float* xb = x + (size_t)b * C_IN * LEN + l;
        u16* row = xt + ((size_t)b * LPAD + lp) * C_IN;
        int key = lp & 15;
        #pragma unroll
        for (int jj = 0; jj < 4; ++jj) {
            int cblk = jb * 4 + jj;
            ushort8 v;
            #pragma unroll
            for (int e = 0; e < 8; ++e)
                v[e] = f2bf(xb[(size_t)(cblk * 8 + e) * LEN]);
            int jstore = cblk ^ key;
            *reinterpret_cast<ushort8*>(row + jstore * 8) = v;
        }
        return;
    }
    if (bid < XT_BLKS + W4_BLKS) {
        int i = (bid - XT_BLKS) * 256 + t;   // exact: 1152*256 == C_OUT*KTOT
        int e  = i & 7;
        int r  = i >> 3;
        int mr = r & 15;
        int kg = (r >> 4) & 3;
        int ob = (r >> 6) & 15;
        int s  = r >> 10;
        int o  = ob * 16 + mr;
        int k  = s >> 2;
        int c  = (s & 3) * 32 + kg * 8 + e;
        w4[i] = f2bf(w[((size_t)o * C_IN + c) * KS + k]);
        return;
    }
    __shared__ float red[256];
    int o = bid - (XT_BLKS + W4_BLKS);
    float sum = 0.f;
    for (int i = t; i < KTOT; i += 256) {
        int k = i % KS;                    // offset layout [c][k]
        float tk = k * 0.01f;              // DT
        float off = vel[i] * tk + 0.5f * acc_in[i] * tk * tk;
        sum += off * w[(size_t)o * KTOT + i];
    }
    red[t] = sum;
    __syncthreads();
    for (int h = 128; h > 0; h >>= 1) {
        if (t < h) red[t] += red[t + h];
        __syncthreads();
    }
    if (t == 0) ebias[o] = bias[o] + red[0];

    if (o == 0) {                          // phys
        __syncthreads();
        float pv = 0.f;
        for (int i = t; i < KTOT; i += 256) {
            float v = vel[i], a = acc_in[i];
            pv += v * v + a * a;
        }
        red[t] = pv;
        __syncthreads();
        for (int h = 128; h > 0; h >>= 1) {
            if (t < h) red[t] += red[t + h];
            __syncthreads();
        }
        if (t == 0) *phys_out = 0.01f * (red[0] / (float)KTOT);
    }
}

// ---------------------------------------------------------------------------
// Main: implicit-GEMM conv, 2-phase counted-vmcnt schedule (T3+T4+T5).
// Block = 256 o x 256 l, 512 threads / 8 waves (2 wm x 4 wn), wave tile
// 128 o x 64 l = 8x4 frags of mfma_f32_16x16x32_bf16.
//  - B (x-tile, 264 rows = 67.6KB) staged ONCE (swizzle pre-baked in data)
//  - A ring-3 (3 x 16KB), stage(s+2) issued during step s (distance 2),
//    end-of-step wait = vmcnt(2): stage(s+1) landed, stage(s+2) in flight
//  - per K-step 2 phases, each {ds_reads + 1 stage-call -> s_barrier ->
//    lgkmcnt(0) -> setprio(1) 16 MFMA setprio(0) -> s_barrier}
//  - 1 block/CU (116.7KB LDS), 2 waves/SIMD at alternating phases
// ---------------------------------------------------------------------------
__global__ __launch_bounds__(512, 2) void conv_main(const u16* __restrict__ xt,
                                                    const u16* __restrict__ w4,
                                                    const float* __restrict__ ebias,
                                                    float* __restrict__ out) {
    __shared__ u16 ldsx[4224 * 8];         // B tile: 264 rows x 256B = 67584 B
    __shared__ u16 ldsa[3][8192];          // A ring: 3 x 16384 B

    int b     = blockIdx.y;
    int lbase = blockIdx.x * 256;
    int t     = threadIdx.x;
    int lane  = t & 63;
    int w     = t >> 6;                    // 0..7
    int wm    = w >> 2;                    // o-half (128 o per wave)
    int wn    = w & 3;                     // l-quarter (64 l per wave)
    int mrow  = lane & 15;
    int kgrp  = lane >> 4;

    // ---- prologue: stage B (67584B) + A(0), A(1)
    {
        const u16* bsrc = xt + ((size_t)b * LPAD + lbase) * C_IN;
        #pragma unroll
        for (int j = 0; j < 8; ++j)        // 8 x 8KB
            g2l16(bsrc + (j * 512 + t) * 8, ldsx + (j * 512 + w * 64) * 8);
        if (t < 128)                       // remaining 128 units (2KB)
            g2l16(bsrc + (4096 + t) * 8, ldsx + (4096 + w * 64) * 8);
        #pragma unroll
        for (int p = 0; p < 2; ++p)
            #pragma unroll
            for (int j = 0; j < 2; ++j)
                g2l16(w4 + (size_t)p * 8192 + (j * 512 + t) * 8,
                      ldsa[p] + (j * 512 + w * 64) * 8);
    }
    // B + A(0) landed; A(1)'s 2 calls may remain in flight
    asm volatile("s_waitcnt vmcnt(2)" ::: "memory");
    __builtin_amdgcn_s_barrier();

    f32x4 acc[8][4] = {};
    const char* ldsbase = reinterpret_cast<const char*>(ldsx);

    #define LOAD_A4(BUF, M0, AF)                                                 \
        {                                                                        \
            const u16* ab_ = ldsa[BUF] + wm * 4096 + (M0) * 512 + lane * 8;      \
            _Pragma("unroll")                                                    \
            for (int mi = 0; mi < 4; ++mi)                                       \
                AF[mi] = *reinterpret_cast<const bf16x8*>(ab_ + mi * 512);       \
        }
    #define LOAD_B4(S, BF)                                                       \
        {                                                                        \
            int k_ = (S) >> 2;                                                   \
            int coff_ = ((S) & 3) * 64 + kgrp * 16;                              \
            _Pragma("unroll")                                                    \
            for (int ni = 0; ni < 4; ++ni) {                                     \
                int row_  = wn * 64 + ni * 16 + mrow + k_;                       \
                int addr_ = row_ * 256 + coff_;                                  \
                addr_ ^= (row_ & 15) << 4;                                       \
                BF[ni] = *reinterpret_cast<const bf16x8*>(ldsbase + addr_);      \
            }                                                                    \
        }
    #define STAGE_J(S, J)                                                        \
        g2l16(w4 + (size_t)(S) * 8192 + ((J) * 512 + t) * 8,                     \
              ldsa[(S) % 3] + ((J) * 512 + w * 64) * 8);
    #define MFMA16(AF, BF, M0)                                                   \
        {                                                                        \
            _Pragma("unroll")                                                    \
            for (int mi = 0; mi < 4; ++mi)                                       \
                _Pragma("unroll")                                                \
                for (int ni = 0; ni < 4; ++ni)                                   \
                    acc[(M0) + mi][ni] = __builtin_amdgcn_mfma_f32_16x16x32_bf16(\
                        AF[mi], BF[ni], acc[(M0) + mi][ni], 0, 0, 0);            \
        }

    #pragma unroll
    for (int s = 0; s < NSTEP; ++s) {
        const int buf = s % 3;
        bf16x8 af[4], bf[4];
        // ---- phase 1: A0-3 + B, stage half 1, MFMA mi 0..3
        LOAD_A4(buf, 0, af);
        LOAD_B4(s, bf);
        if (s + 2 < NSTEP) STAGE_J(s + 2, 0)
        __builtin_amdgcn_s_barrier();
        asm volatile("s_waitcnt lgkmcnt(0)" ::: "memory");
        __builtin_amdgcn_sched_barrier(0);
        __builtin_amdgcn_s_setprio(1);
        MFMA16(af, bf, 0);
        __builtin_amdgcn_s_setprio(0);
        __builtin_amdgcn_s_barrier();
        // ---- phase 2: A4-7, stage half 2, MFMA mi 4..7
        LOAD_A4(buf, 4, af);
        if (s + 2 < NSTEP) STAGE_J(s + 2, 1)
        __builtin_amdgcn_s_barrier();
        asm volatile("s_waitcnt lgkmcnt(0)" ::: "memory");
        __builtin_amdgcn_sched_barrier(0);
        __builtin_amdgcn_s_setprio(1);
        MFMA16(af, bf, 4);
        __builtin_amdgcn_s_setprio(0);
        // end-of-step: ensure stage(s+1) landed before next step reads it;
        // keep stage(s+2) in flight (counted vmcnt, never 0 mid-loop)
        if (s + 2 < NSTEP)      asm volatile("s_waitcnt vmcnt(2)" ::: "memory");
        else if (s + 1 < NSTEP) asm volatile("s_waitcnt vmcnt(0)" ::: "memory");
        __builtin_amdgcn_s_barrier();
    }

    // ---- epilogue: D layout col = lane&15 (l), row = (lane>>4)*4 + r (o)
    #pragma unroll
    for (int mi = 0; mi < 8; ++mi) {
        int o0 = (wm * 8 + mi) * 16 + kgrp * 4;
        f32x4 eb = *reinterpret_cast<const f32x4*>(ebias + o0);
        #pragma unroll
        for (int ni = 0; ni < 4; ++ni) {
            int l = lbase + wn * 64 + ni * 16 + mrow;
            float* op = out + (size_t)(b * C_OUT + o0) * LEN + l;
            #pragma unroll
            for (int r = 0; r < 4; ++r)
                op[(size_t)r * LEN] = acc[mi][ni][r] + eb[r];
        }
    }
    #undef LOAD_A4
    #undef LOAD_B4
    #undef STAGE_J
    #undef MFMA16
}

extern "C" void kernel_launch(void* const* d_in, const int* in_sizes, int n_in,
                              void* d_out, int out_size, void* d_ws, size_t ws_size,
                              hipStream_t stream) {
    const float* x      = (const float*)d_in[0];
    const float* weight = (const float*)d_in[1];
    const float* bias   = (const float*)d_in[2];
    const float* vel    = (const float*)d_in[3];
    const float* acc    = (const float*)d_in[4];
    float* out = (float*)d_out;

    char* ws = (char*)d_ws;
    u16*  xt    = (u16*)ws;                                       // 16,797,696 B
    u16*  w4    = (u16*)(ws + (size_t)BATCH * LPAD * C_IN * 2);   // 589,824 B
    float* ebias = (float*)(ws + (size_t)BATCH * LPAD * C_IN * 2 + (size_t)C_OUT * KTOT * 2);

    hipLaunchKernelGGL(prep_all, dim3(XT_BLKS + W4_BLKS + EB_BLKS), dim3(256), 0, stream,
                       x, weight, bias, vel, acc, xt, w4, ebias,
                       out + (size_t)BATCH * C_OUT * LEN);
    hipLaunchKernelGGL(conv_main, dim3(LEN / 256, BATCH), dim3(512), 0, stream,
                       xt, w4, ebias, out);
}